// Round 1
// baseline (185.833 us; speedup 1.0000x reference)
//
#include <hip/hip_runtime.h>
#include <stdint.h>

#define N 8192

typedef __attribute__((ext_vector_type(8))) short sh8;
typedef __attribute__((ext_vector_type(4))) float f32x4;

static __device__ __forceinline__ unsigned short f2bf(float f) {
    union { float f; unsigned u; } v; v.f = f;
    unsigned r = v.u + 0x7FFF + ((v.u >> 16) & 1);   // round-to-nearest-even
    return (unsigned short)(r >> 16);
}

static __device__ __forceinline__ float bf2f(unsigned short h) {
    union { unsigned u; float f; } v; v.u = ((unsigned)h) << 16;
    return v.f;
}

// Pass 1: deg[i] = row-sum of adj; write bf16 copy of (adj + I).
__global__ __launch_bounds__(256) void k_deg_conv(const float* __restrict__ adj,
        unsigned short* __restrict__ abf, float* __restrict__ deg) {
    int row = blockIdx.x;
    const float* arow = adj + (size_t)row * N;
    unsigned short* brow = abf + (size_t)row * N;
    int t = threadIdx.x;
    float sum = 0.f;
    #pragma unroll
    for (int it = 0; it < N / 1024; ++it) {      // 8 iters of float4 per thread
        int j = (it * 256 + t) * 4;
        float4 v = *(const float4*)(arow + j);
        sum += v.x + v.y + v.z + v.w;
        float w4[4] = {v.x, v.y, v.z, v.w};
        if (row >= j && row < j + 4) w4[row - j] += 1.0f;   // a = adj + I
        ushort4 o;
        o.x = f2bf(w4[0]); o.y = f2bf(w4[1]); o.z = f2bf(w4[2]); o.w = f2bf(w4[3]);
        *(ushort4*)(brow + j) = o;
    }
    __shared__ float red[256];
    red[t] = sum; __syncthreads();
    for (int sz = 128; sz > 0; sz >>= 1) {
        if (t < sz) red[t] += red[t + sz];
        __syncthreads();
    }
    if (t == 0) deg[row] = red[0];
}

// Pass 2 (single block): gmax, then per-node scalars s, y0 = s, y1 = s*deg_norm.
__global__ __launch_bounds__(1024) void k_scalars(const float* __restrict__ deg,
        float* __restrict__ s, float* __restrict__ y0, float* __restrict__ y1) {
    __shared__ float red[1024];
    int t = threadIdx.x;
    float m = 1.0f;
    for (int i = t; i < N; i += 1024) m = fmaxf(m, deg[i]);
    red[t] = m; __syncthreads();
    for (int sz = 512; sz > 0; sz >>= 1) {
        if (t < sz) red[t] = fmaxf(red[t], red[t + sz]);
        __syncthreads();
    }
    float gmax = red[0];
    for (int i = t; i < N; i += 1024) {
        float d = deg[i];
        float si = 1.0f / sqrtf(fmaxf(d + 1.0f, 1.0f));
        s[i] = si;
        y0[i] = si;
        y1[i] = si * (d / gmax);
    }
}

// Pass 3: one wave per row. z = a_row . [y0, y1]; h1 = relu(s_i*z@W1 + b1);
// store gT[c][i] = bf16(s_i * h1[i][c])  (transposed for MFMA B-operand reads).
__global__ __launch_bounds__(256) void k_layer1(const unsigned short* __restrict__ abf,
        const float* __restrict__ y0, const float* __restrict__ y1,
        const float* __restrict__ s, const float* __restrict__ W1,
        const float* __restrict__ b1, unsigned short* __restrict__ gT) {
    int wave = threadIdx.x >> 6;
    int lane = threadIdx.x & 63;
    int row = blockIdx.x * 4 + wave;
    const unsigned short* arow = abf + (size_t)row * N;
    float z0 = 0.f, z1 = 0.f;
    #pragma unroll 2
    for (int it = 0; it < N / 512; ++it) {   // 16 iters, 8 elems/lane/iter
        int j = it * 512 + lane * 8;
        sh8 a = *(const sh8*)(arow + j);
        float4 p0 = *(const float4*)(y0 + j);
        float4 p1 = *(const float4*)(y0 + j + 4);
        float4 q0 = *(const float4*)(y1 + j);
        float4 q1 = *(const float4*)(y1 + j + 4);
        float af[8];
        #pragma unroll
        for (int e = 0; e < 8; ++e) af[e] = bf2f((unsigned short)a[e]);
        z0 += af[0]*p0.x + af[1]*p0.y + af[2]*p0.z + af[3]*p0.w
            + af[4]*p1.x + af[5]*p1.y + af[6]*p1.z + af[7]*p1.w;
        z1 += af[0]*q0.x + af[1]*q0.y + af[2]*q0.z + af[3]*q0.w
            + af[4]*q1.x + af[5]*q1.y + af[6]*q1.z + af[7]*q1.w;
    }
    #pragma unroll
    for (int m = 1; m < 64; m <<= 1) {
        z0 += __shfl_xor(z0, m);
        z1 += __shfl_xor(z1, m);
    }
    float si = s[row];
    float h = si * (z0 * W1[lane] + z1 * W1[64 + lane]) + b1[lane];
    h = fmaxf(h, 0.f);
    gT[(size_t)lane * N + row] = f2bf(si * h);
}

// Pass 4: t = a @ g  (M=8192, N=64, K=8192, bf16 MFMA 16x16x32),
// out = s_i * (t @ W2) + b2. Block = 16 rows, 4 waves K-split (2048 each).
__global__ __launch_bounds__(256) void k_layer2(const unsigned short* __restrict__ abf,
        const unsigned short* __restrict__ gT, const float* __restrict__ s,
        const float* __restrict__ W2, const float* __restrict__ b2,
        float* __restrict__ out) {
    __shared__ float tl[4][16 * 65];
    int tid = threadIdx.x;
    int wave = tid >> 6, lane = tid & 63;
    int r0 = blockIdx.x * 16;
    int arow = r0 + (lane & 15);
    int kb0 = wave * 2048 + ((lane >> 4) * 8);
    const unsigned short* aptr = abf + (size_t)arow * N + kb0;
    const unsigned short* gbase = gT + kb0;
    int col = lane & 15;
    f32x4 acc0 = {0,0,0,0}, acc1 = {0,0,0,0}, acc2 = {0,0,0,0}, acc3 = {0,0,0,0};
    #pragma unroll 4
    for (int kk = 0; kk < 64; ++kk) {       // 64 * 32 = 2048 K per wave
        sh8 a  = *(const sh8*)(aptr + kk * 32);
        sh8 b0 = *(const sh8*)(gbase + (size_t)(col      ) * N + kk * 32);
        sh8 b1v= *(const sh8*)(gbase + (size_t)(col + 16) * N + kk * 32);
        sh8 b2v= *(const sh8*)(gbase + (size_t)(col + 32) * N + kk * 32);
        sh8 b3v= *(const sh8*)(gbase + (size_t)(col + 48) * N + kk * 32);
        acc0 = __builtin_amdgcn_mfma_f32_16x16x32_bf16(a, b0,  acc0, 0, 0, 0);
        acc1 = __builtin_amdgcn_mfma_f32_16x16x32_bf16(a, b1v, acc1, 0, 0, 0);
        acc2 = __builtin_amdgcn_mfma_f32_16x16x32_bf16(a, b2v, acc2, 0, 0, 0);
        acc3 = __builtin_amdgcn_mfma_f32_16x16x32_bf16(a, b3v, acc3, 0, 0, 0);
    }
    // C/D layout (m89-verified): col = lane&15, row = (lane>>4)*4 + reg
    int lr = (lane >> 4) * 4, lc = lane & 15;
    #pragma unroll
    for (int r = 0; r < 4; ++r) {
        tl[wave][(lr + r) * 65 + lc     ] = acc0[r];
        tl[wave][(lr + r) * 65 + lc + 16] = acc1[r];
        tl[wave][(lr + r) * 65 + lc + 32] = acc2[r];
        tl[wave][(lr + r) * 65 + lc + 48] = acc3[r];
    }
    __syncthreads();
    // reduce the 4 K-split partials into tl[0]
    for (int v = tid; v < 16 * 64; v += 256) {
        int idx = (v >> 6) * 65 + (v & 63);
        tl[0][idx] = tl[0][idx] + tl[1][idx] + tl[2][idx] + tl[3][idx];
    }
    __syncthreads();
    // epilogue: out[row][c2] = s[row] * dot(t[row,:], W2[:,c2]) + b2[c2]
    int c2 = tid & 63, rg = tid >> 6;
    float acc[4] = {0.f, 0.f, 0.f, 0.f};
    for (int c = 0; c < 64; ++c) {
        float w = W2[c * 64 + c2];
        #pragma unroll
        for (int r = 0; r < 4; ++r) acc[r] += tl[0][(rg * 4 + r) * 65 + c] * w;
    }
    float bc = b2[c2];
    #pragma unroll
    for (int r = 0; r < 4; ++r) {
        int row = r0 + rg * 4 + r;
        out[(size_t)row * 64 + c2] = s[row] * acc[r] + bc;
    }
}

extern "C" void kernel_launch(void* const* d_in, const int* in_sizes, int n_in,
                              void* d_out, int out_size, void* d_ws, size_t ws_size,
                              hipStream_t stream) {
    const float* adj = (const float*)d_in[0];
    const float* W1  = (const float*)d_in[1];
    const float* b1  = (const float*)d_in[2];
    const float* W2  = (const float*)d_in[3];
    const float* b2  = (const float*)d_in[4];
    float* out = (float*)d_out;

    char* ws = (char*)d_ws;
    unsigned short* abf = (unsigned short*)ws;                              // 128 MB
    unsigned short* gT  = (unsigned short*)(ws + (size_t)N * N * 2);        // 1 MB
    float* deg = (float*)(ws + (size_t)N * N * 2 + (size_t)64 * N * 2);
    float* s   = deg + N;
    float* y0  = s + N;
    float* y1  = y0 + N;

    hipLaunchKernelGGL(k_deg_conv, dim3(N),      dim3(256),  0, stream, adj, abf, deg);
    hipLaunchKernelGGL(k_scalars,  dim3(1),      dim3(1024), 0, stream, deg, s, y0, y1);
    hipLaunchKernelGGL(k_layer1,   dim3(N / 4),  dim3(256),  0, stream, abf, y0, y1, s, W1, b1, gT);
    hipLaunchKernelGGL(k_layer2,   dim3(N / 16), dim3(256),  0, stream, abf, gT, s, W2, b2, out);
}